// Round 11
// baseline (55409.131 us; speedup 1.0000x reference)
//
#include <hip/hip_runtime.h>

typedef unsigned short u16;
typedef unsigned int u32;
typedef __attribute__((ext_vector_type(4))) unsigned int u32x4;
typedef _Float16 half_t;
typedef __attribute__((ext_vector_type(2))) _Float16 h2;

#define DI static __device__ __forceinline__

// ---------------- workspace layout (bytes) ----------------
constexpr size_t OFF_WKQ = 0;                          // 256x256 f32 (scale*Wk@Wq^T)
constexpr size_t OFF_WVW = OFF_WKQ + 256*256*4;        // 256x128 f32 (Wv@W3)
constexpr size_t OFF_WB  = OFF_WVW + 256*128*4;        // 256 f32 (scale*Wk@bq)
constexpr size_t OFF_BYV = OFF_WB  + 256*4;            // 128 f32 (b3 + bv@W3)
constexpr size_t OFF_BG  = OFF_BYV + 128*4;            // 2048 f32 (bih+bhh)
constexpr size_t OFF_W1H = OFF_BG  + 2048*4;           // f16 [16][256][8]   (W1 k-tiled)
constexpr size_t OFF_WGH = OFF_W1H + 128*256*2;        // f16 [96][2048][8]  ([Wih;Whh] k-tiled)
constexpr size_t OFF_W2H = OFF_WGH + 768*2048*2;       // f16 [256][512]     (W2 col-major)
constexpr size_t OFF_S0  = OFF_W2H + 256*512*2;        // 65536 f32 (incl. mask bias)
constexpr size_t OFF_KT2 = OFF_S0  + 65536*4;          // f16 [64][32][1024][8]  (kt k-tiled)
constexpr size_t OFF_VW2 = OFF_KT2 + (size_t)64*1024*256*2; // f16 [64][512][128][2] (vw l-paired)

DI float sigm(float x){ return 1.f/(1.f + __expf(-x)); }
DI float tanh_(float x){ return 1.f - 2.f/(__expf(2.f*x) + 1.f); }
DI u16 f2h(float f){ half_t h = (half_t)f; return __builtin_bit_cast(u16, h); }
DI u32 pk2(float a, float b){ return (u32)f2h(a) | ((u32)f2h(b) << 16); }
DI h2 u32h2(u32 v){ return __builtin_bit_cast(h2, v); }

DI float fdot2f(h2 a, h2 b, float c){
#if defined(__has_builtin) && __has_builtin(__builtin_amdgcn_fdot2)
  return __builtin_amdgcn_fdot2(a, b, c, false);
#else
  return c + (float)a[0]*(float)b[0] + (float)a[1]*(float)b[1];
#endif
}

// ---------------- one-time weight prep ----------------
__global__ __launch_bounds__(256) void kPrep(char* ws,
    const float* W1, const float* Wih, const float* Whh, const float* W2,
    const float* Wq, const float* bq, const float* Wk, const float* bk,
    const float* Wv, const float* bv, const float* W3, const float* b3,
    const float* bih, const float* bhh)
{
  const int wg = blockIdx.x, tid = threadIdx.x;
  if (wg < 64) {                       // Wkq[e][d] = scale * dot(Wk row e, Wq row d)
    float* Wkq = (float*)(ws + OFF_WKQ);
    for (int rr = 0; rr < 4; ++rr) {
      const int e = wg*4 + rr;
      float acc = 0.f;
      for (int d = 0; d < 256; ++d) acc = fmaf(Wk[e*256+d], Wq[tid*256+d], acc);
      Wkq[e*256 + tid] = acc * 0.0625f;
    }
  } else if (wg < 96) {                // Wvw[e][o] = dot(Wv row e, W3 col o)
    float* Wvw = (float*)(ws + OFF_WVW);
    if (tid < 128) {
      for (int rr = 0; rr < 8; ++rr) {
        const int e = (wg-64)*8 + rr;
        float acc = 0.f;
        for (int d = 0; d < 256; ++d) acc = fmaf(Wv[e*256+d], W3[d*128+tid], acc);
        Wvw[e*128 + tid] = acc;
      }
    }
  } else if (wg == 96) {               // wb, byv
    float* wb = (float*)(ws + OFF_WB);
    float acc = 0.f;
    for (int d = 0; d < 256; ++d) acc = fmaf(Wk[tid*256+d], bq[d], acc);
    wb[tid] = acc * 0.0625f;
    if (tid < 128) {
      float* byv = (float*)(ws + OFF_BYV);
      float a2 = b3[tid];
      for (int d = 0; d < 256; ++d) a2 = fmaf(bv[d], W3[d*128+tid], a2);
      byv[tid] = a2;
    }
  } else if (wg == 97) {               // bg = bih + bhh
    float* bg = (float*)(ws + OFF_BG);
    for (int j = tid; j < 2048; j += 256) bg[j] = bih[j] + bhh[j];
  } else if (wg < 106) {               // W1 -> f16 k-tiled [k/8][256][8]
    u16* W1h = (u16*)(ws + OFF_W1H);
    const int k0 = (wg - 98)*16;
    for (int kk = 0; kk < 16; ++kk) {
      const int k = k0 + kk;
      W1h[((k>>3)*256 + tid)*8 + (k&7)] = f2h(W1[k*256 + tid]);
    }
  } else if (wg < 170) {               // [Wih;Whh] -> f16 k-tiled [k/8][2048][8]
    u16* Wgh = (u16*)(ws + OFF_WGH);
    const int k0 = (wg - 106)*12;
    for (int kk = 0; kk < 12; ++kk) {
      const int k = k0 + kk;
      for (int n = tid; n < 2048; n += 256) {
        const float src = (k < 256) ? Wih[k*2048 + n] : Whh[(k-256)*2048 + n];
        Wgh[((k>>3)*2048 + n)*8 + (k&7)] = f2h(src);
      }
    }
  } else if (wg < 178) {               // W2 -> f16 col-major [n][512]
    u16* W2h = (u16*)(ws + OFF_W2H);
    const int n0 = (wg - 170)*32;
    for (int nn = 0; nn < 32; ++nn) {
      const int n = n0 + nn;
      for (int k = tid; k < 512; k += 256) W2h[n*512 + k] = f2h(W2[k*256 + n]);
    }
  }
}

// ---------------- precompute kt2, vw2, s0 (mask bias folded in) ----------------
__global__ __launch_bounds__(256) void kKTVW(char* __restrict__ ws, const float* __restrict__ hid_r,
                                             const float* __restrict__ in_mask)
{
  const int wg = blockIdx.x, tid = threadIdx.x;
  __shared__ float lh[256*36];  // [e][r], padded to 36
  const float* Wkq = (const float*)(ws + OFF_WKQ);
  const float* Wvw = (const float*)(ws + OFF_WVW);
  const float* wb  = (const float*)(ws + OFF_WB);
  u16* kt2 = (u16*)(ws + OFF_KT2);
  u16* vw2 = (u16*)(ws + OFF_VW2);
  float* s0 = (float*)(ws + OFF_S0);
  const size_t r0 = (size_t)wg * 32;
  for (int idx = tid; idx < 32*256; idx += 256) {
    const int e = idx & 255, r = idx >> 8;
    lh[e*36 + r] = hid_r[(r0 + r)*256 + e];
  }
  __syncthreads();
  float acc[32];
  #pragma unroll
  for (int r = 0; r < 32; ++r) acc[r] = 0.f;
  for (int e = 0; e < 256; ++e) {
    const float wv = Wkq[e*256 + tid];
    #pragma unroll
    for (int r4 = 0; r4 < 8; ++r4) {
      const float4 l4 = *(const float4*)&lh[e*36 + r4*4];
      acc[r4*4+0] = fmaf(l4.x, wv, acc[r4*4+0]);
      acc[r4*4+1] = fmaf(l4.y, wv, acc[r4*4+1]);
      acc[r4*4+2] = fmaf(l4.z, wv, acc[r4*4+2]);
      acc[r4*4+3] = fmaf(l4.w, wv, acc[r4*4+3]);
    }
  }
  // kt2 layout: [b][k/8][row 1024][8]
  for (int r = 0; r < 32; ++r) {
    const size_t row = r0 + r;
    const size_t bb = row >> 10;
    const int l = (int)(row & 1023);
    kt2[(((bb*32) + (size_t)(tid>>3))*1024 + l)*8 + (tid&7)] = f2h(acc[r]);
  }
  if (tid < 128) {
    #pragma unroll
    for (int r = 0; r < 32; ++r) acc[r] = 0.f;
    for (int e = 0; e < 256; ++e) {
      const float wv = Wvw[e*128 + tid];
      #pragma unroll
      for (int r4 = 0; r4 < 8; ++r4) {
        const float4 l4 = *(const float4*)&lh[e*36 + r4*4];
        acc[r4*4+0] = fmaf(l4.x, wv, acc[r4*4+0]);
        acc[r4*4+1] = fmaf(l4.y, wv, acc[r4*4+1]);
        acc[r4*4+2] = fmaf(l4.z, wv, acc[r4*4+2]);
        acc[r4*4+3] = fmaf(l4.w, wv, acc[r4*4+3]);
      }
    }
    // vw2 layout: [b][l/2][d 128][2]
    for (int r = 0; r < 32; ++r) {
      const size_t row = r0 + r;
      const size_t bb = row >> 10;
      const int l = (int)(row & 1023);
      vw2[((bb*512) + (size_t)(l>>1))*256 + tid*2 + (l&1)] = f2h(acc[r]);
    }
  } else if (tid < 160) {
    const int r = tid - 128;
    float a3 = 0.f;
    for (int e = 0; e < 256; ++e) a3 = fmaf(lh[e*36 + r], wb[e], a3);
    s0[r0 + r] = a3 + (in_mask[r0 + r] == 0.f ? -1e9f : 0.f);
  }
}

// ---------------- persistent per-batch kernel: whole scan, zero inter-WG sync ----------------
__global__ __launch_bounds__(1024) void kMain(char* __restrict__ ws, const float* __restrict__ init_in,
    const float* __restrict__ in_mask, const float* __restrict__ b1g, const float* __restrict__ b2g,
    const float* __restrict__ h0, const float* __restrict__ c0, float* __restrict__ dout)
{
  const int b = blockIdx.x, tid = threadIdx.x;
  const int hl = tid & 31, unit = tid >> 5;

  __shared__ __align__(16) u32 x2[384];     // f16 pairs: [a(0..127) ; h(128..383)]
  __shared__ __align__(16) u32 yh2[64];     // y f16 pairs
  __shared__ __align__(16) u32 dxh2[128];   // dx f16 pairs
  __shared__ __align__(16) u32 eh2[512];    // e f16 pairs
  __shared__ float gt[2048];
  __shared__ float cst[512];
  __shared__ float s0l[1024];
  __shared__ float sc[1024];                // scores, then e
  __shared__ float red[256*33];
  __shared__ float mrg[32*132];
  __shared__ float rtmp[64];
  __shared__ float fin[2];

  const u16* W1h = (const u16*)(ws + OFF_W1H);
  const u16* Wgh = (const u16*)(ws + OFF_WGH);
  const u16* W2h = (const u16*)(ws + OFF_W2H);
  const u16* kt2 = (const u16*)(ws + OFF_KT2) + (size_t)b*32*1024*8;
  const u16* vw2 = (const u16*)(ws + OFF_VW2) + (size_t)b*512*256;
  const float* s0g = (const float*)(ws + OFF_S0) + b*1024;
  const float* bgg = (const float*)(ws + OFF_BG);
  const float* byv = (const float*)(ws + OFF_BYV);
  float* attn = dout + (size_t)64*1024*128;

  // init state
  if (tid < 512) cst[tid] = c0[b*512 + tid];
  if (tid < 256) x2[128 + tid] = pk2(h0[b*512 + 2*tid], h0[b*512 + 2*tid + 1]);
  if (tid < 64)  yh2[tid] = pk2(init_in[b*128 + 2*tid], init_in[b*128 + 2*tid + 1]);
  s0l[tid] = s0g[tid];
  __syncthreads();

  for (int s = 0; s < 1024; ++s) {
    // ---- A: a = relu(y@W1 + b1) -> x2[0..127] ----
    if (tid < 256) {
      float acc = b1g[tid];
      #pragma unroll 4
      for (int r = 0; r < 16; ++r) {
        const u32x4 wv = *(const u32x4*)(W1h + ((r*256 + tid) << 3));
        const u32x4 xq = *(const u32x4*)&yh2[r*4];
        acc = fdot2f(u32h2(wv[0]), u32h2(xq[0]), acc);
        acc = fdot2f(u32h2(wv[1]), u32h2(xq[1]), acc);
        acc = fdot2f(u32h2(wv[2]), u32h2(xq[2]), acc);
        acc = fdot2f(u32h2(wv[3]), u32h2(xq[3]), acc);
      }
      ((u16*)x2)[tid] = f2h(fmaxf(acc, 0.f));
    }
    __syncthreads();
    // ---- B: gates = x@[Wih;Whh] + bg ; thread owns cols tid and tid+1024 ----
    {
      float g0 = bgg[tid], g1 = bgg[tid + 1024];
      #pragma unroll 4
      for (int r = 0; r < 96; ++r) {
        const u32x4 w0 = *(const u32x4*)(Wgh + (((r << 11) + tid) << 3));
        const u32x4 w1 = *(const u32x4*)(Wgh + (((r << 11) + tid + 1024) << 3));
        const u32x4 xq = *(const u32x4*)&x2[r*4];
        g0 = fdot2f(u32h2(w0[0]), u32h2(xq[0]), g0);
        g0 = fdot2f(u32h2(w0[1]), u32h2(xq[1]), g0);
        g0 = fdot2f(u32h2(w0[2]), u32h2(xq[2]), g0);
        g0 = fdot2f(u32h2(w0[3]), u32h2(xq[3]), g0);
        g1 = fdot2f(u32h2(w1[0]), u32h2(xq[0]), g1);
        g1 = fdot2f(u32h2(w1[1]), u32h2(xq[1]), g1);
        g1 = fdot2f(u32h2(w1[2]), u32h2(xq[2]), g1);
        g1 = fdot2f(u32h2(w1[3]), u32h2(xq[3]), g1);
      }
      gt[tid] = g0; gt[tid + 1024] = g1;
    }
    __syncthreads();
    // ---- C: h,c update ----
    if (tid < 512) {
      const float gi = gt[tid], gf = gt[512 + tid], gg = gt[1024 + tid], go = gt[1536 + tid];
      const float cn = sigm(gf)*cst[tid] + sigm(gi)*tanh_(gg);
      const float h  = sigm(go)*tanh_(cn);
      cst[tid] = cn;
      ((u16*)x2)[256 + tid] = f2h(h);
    }
    __syncthreads();
    // ---- D: dx = relu(h@W2 + b2); unit owns 8 cols, lane k-chunk 16 ----
    {
      const u32x4 ha = *(const u32x4*)&x2[128 + hl*8];
      const u32x4 hb = *(const u32x4*)&x2[128 + hl*8 + 4];
      #pragma unroll
      for (int j = 0; j < 8; ++j) {
        const int n = unit*8 + j;
        const u32x4 w0 = *(const u32x4*)(W2h + n*512 + hl*16);
        const u32x4 w1 = *(const u32x4*)(W2h + n*512 + hl*16 + 8);
        float acc = 0.f;
        acc = fdot2f(u32h2(ha[0]), u32h2(w0[0]), acc);
        acc = fdot2f(u32h2(ha[1]), u32h2(w0[1]), acc);
        acc = fdot2f(u32h2(ha[2]), u32h2(w0[2]), acc);
        acc = fdot2f(u32h2(ha[3]), u32h2(w0[3]), acc);
        acc = fdot2f(u32h2(hb[0]), u32h2(w1[0]), acc);
        acc = fdot2f(u32h2(hb[1]), u32h2(w1[1]), acc);
        acc = fdot2f(u32h2(hb[2]), u32h2(w1[2]), acc);
        acc = fdot2f(u32h2(hb[3]), u32h2(w1[3]), acc);
        red[n*33 + hl] = acc;
      }
    }
    __syncthreads();
    if (tid < 256) {
      float a = 0.f;
      #pragma unroll
      for (int l = 0; l < 32; ++l) a += red[tid*33 + l];
      const float dx = fmaxf(a + b2g[tid], 0.f);
      ((u16*)dxh2)[tid] = f2h(dx);
    }
    __syncthreads();
    // ---- E: scores; one row per thread (no shuffles) ----
    {
      float st = s0l[tid];
      #pragma unroll 4
      for (int r = 0; r < 32; ++r) {
        const u32x4 kv = __builtin_nontemporal_load((const u32x4*)(kt2 + (((size_t)r << 10) + tid)*8));
        const u32x4 xq = *(const u32x4*)&dxh2[r*4];
        st = fdot2f(u32h2(kv[0]), u32h2(xq[0]), st);
        st = fdot2f(u32h2(kv[1]), u32h2(xq[1]), st);
        st = fdot2f(u32h2(kv[2]), u32h2(xq[2]), st);
        st = fdot2f(u32h2(kv[3]), u32h2(xq[3]), st);
      }
      sc[tid] = st;
    }
    __syncthreads();
    // ---- F: block softmax (max, e, S) ----
    if (tid < 64) {
      float m = -1e30f;
      #pragma unroll
      for (int i = 0; i < 16; ++i) m = fmaxf(m, sc[tid*16 + i]);
      rtmp[tid] = m;
    }
    __syncthreads();
    if (tid < 64) {
      float m = rtmp[tid];
      #pragma unroll
      for (int d = 32; d >= 1; d >>= 1) m = fmaxf(m, __shfl_xor(m, d, 64));
      if (tid == 0) fin[0] = m;
    }
    __syncthreads();
    {
      const float e = __expf(sc[tid] - fin[0]);
      sc[tid] = e;
      ((u16*)eh2)[tid] = f2h(e);
    }
    __syncthreads();
    if (tid < 64) {
      float ssum = 0.f;
      #pragma unroll
      for (int i = 0; i < 16; ++i) ssum += sc[tid*16 + i];
      rtmp[tid] = ssum;
    }
    __syncthreads();
    if (tid < 64) {
      float ssum = rtmp[tid];
      #pragma unroll
      for (int d = 32; d >= 1; d >>= 1) ssum += __shfl_xor(ssum, d, 64);
      if (tid == 0) fin[1] = ssum;
    }
    __syncthreads();
    // ---- G: ctx = sum e_l * vw_l ; unit owns 32 rows (16 l-pairs), lane 4 cols ----
    {
      float cx0 = 0.f, cx1 = 0.f, cx2 = 0.f, cx3 = 0.f;
      #pragma unroll 4
      for (int lp = 0; lp < 16; ++lp) {
        const int lpi = unit*16 + lp;
        const u32x4 vv = __builtin_nontemporal_load((const u32x4*)(vw2 + lpi*256 + hl*8));
        const h2 e2 = u32h2(eh2[lpi]);
        cx0 = fdot2f(e2, u32h2(vv[0]), cx0);
        cx1 = fdot2f(e2, u32h2(vv[1]), cx1);
        cx2 = fdot2f(e2, u32h2(vv[2]), cx2);
        cx3 = fdot2f(e2, u32h2(vv[3]), cx3);
      }
      mrg[unit*132 + 4 + hl*4 + 0] = cx0;
      mrg[unit*132 + 4 + hl*4 + 1] = cx1;
      mrg[unit*132 + 4 + hl*4 + 2] = cx2;
      mrg[unit*132 + 4 + hl*4 + 3] = cx3;
    }
    __syncthreads();
    // ---- H: outputs + y for next step ----
    {
      const float inv = 1.f / fin[1];
      __builtin_nontemporal_store(sc[tid]*inv, &attn[((size_t)b*1024 + s)*1024 + tid]);
      if (tid < 128) {
        float cxs = 0.f;
        #pragma unroll
        for (int u = 0; u < 32; ++u) cxs += mrg[u*132 + 4 + tid];
        const float y = fmaxf(cxs*inv + byv[tid], 0.f);
        __builtin_nontemporal_store(y*in_mask[b*1024 + s], &dout[((size_t)b*1024 + s)*128 + tid]);
        ((u16*)yh2)[tid] = f2h(y);
      }
    }
    __syncthreads();
  }
}

extern "C" void kernel_launch(void* const* d_in, const int* in_sizes, int n_in,
                              void* d_out, int out_size, void* d_ws, size_t ws_size,
                              hipStream_t stream)
{
  (void)in_sizes; (void)n_in; (void)out_size; (void)ws_size;
  const float* hid_r  = (const float*)d_in[0];
  const float* in_mask= (const float*)d_in[1];
  const float* init_in= (const float*)d_in[2];
  const float* h0     = (const float*)d_in[3];
  const float* c0     = (const float*)d_in[4];
  const float* W1     = (const float*)d_in[5];
  const float* b1     = (const float*)d_in[6];
  const float* Wih    = (const float*)d_in[7];
  const float* Whh    = (const float*)d_in[8];
  const float* bih    = (const float*)d_in[9];
  const float* bhh    = (const float*)d_in[10];
  const float* W2     = (const float*)d_in[11];
  const float* b2     = (const float*)d_in[12];
  const float* Wq     = (const float*)d_in[13];
  const float* bq     = (const float*)d_in[14];
  const float* Wk     = (const float*)d_in[15];
  const float* bk     = (const float*)d_in[16];
  const float* Wv     = (const float*)d_in[17];
  const float* bv     = (const float*)d_in[18];
  const float* W3     = (const float*)d_in[19];
  const float* b3     = (const float*)d_in[20];
  char* ws = (char*)d_ws;
  float* out = (float*)d_out;

  hipLaunchKernelGGL(kPrep, dim3(178), dim3(256), 0, stream, ws,
                     W1, Wih, Whh, W2, Wq, bq, Wk, bk, Wv, bv, W3, b3, bih, bhh);
  hipLaunchKernelGGL(kKTVW, dim3(2048), dim3(256), 0, stream, ws, hid_r, in_mask);
  hipLaunchKernelGGL(kMain, dim3(64), dim3(1024), 0, stream, ws,
                     init_in, in_mask, b1, b2, h0, c0, out);
}

// Round 12
// 33006.720 us; speedup vs baseline: 1.6787x; 1.6787x over previous
//
#include <hip/hip_runtime.h>

typedef unsigned short u16;
typedef unsigned int u32;
typedef __attribute__((ext_vector_type(8))) short bf16x8;
typedef __attribute__((ext_vector_type(8))) unsigned short u16x8;
typedef __attribute__((ext_vector_type(4))) unsigned short u16x4;
typedef __attribute__((ext_vector_type(4))) float f32x4;

#define DI static __device__ __forceinline__

// ---------------- workspace layout (bytes) ----------------
constexpr size_t OFF_WKQ  = 0;                               // 256x256 f32  (scale*Wk@Wq^T)
constexpr size_t OFF_WVW  = OFF_WKQ  + 256*256*4;            // 256x128 f32  (Wv@W3)
constexpr size_t OFF_WB   = OFF_WVW  + 256*128*4;            // 256 f32      (scale*Wk@bq)
constexpr size_t OFF_BYV  = OFF_WB   + 256*4;                // 128 f32      (b3 + bv@W3)
constexpr size_t OFF_BG   = OFF_BYV  + 128*4;                // 2048 f32     (bih+bhh)
constexpr size_t OFF_W2T  = OFF_BG   + 2048*4;               // 256x512 bf16 (W2 transposed [n][k])
constexpr size_t OFF_W1F  = OFF_W2T  + 256*512*2;            // 16*4*64*8 bf16 (frag-swizzled W1)
constexpr size_t OFF_WIHF = OFF_W1F  + 16*4*64*8*2;          // 128*8*64*8 bf16
constexpr size_t OFF_WHHF = OFF_WIHF + 128*8*64*8*2;         // 128*16*64*8 bf16
constexpr size_t OFF_KT   = OFF_WHHF + 128*16*64*8*2;        // 64*1024*256 bf16
constexpr size_t OFF_VW   = OFF_KT   + (size_t)64*1024*256*2;// 64*1024*128 bf16
constexpr size_t OFF_S0   = OFF_VW   + (size_t)64*1024*128*2;// 65536 f32 (incl. mask bias)
constexpr size_t OFF_CB   = OFF_S0   + 65536*4;              // 64x512 f32 cell state
constexpr size_t OFF_HF   = OFF_CB   + 64*512*4;             // 64x512 f32 h
constexpr size_t OFF_HFR  = OFF_HF   + 64*512*4;             // 2 x (16*4*64*8) bf16 h frags (ping-pong)
constexpr size_t OFF_SC   = OFF_HFR  + 2*16*4*64*8*2;        // 2 x 64x1024 f32 raw scores (ping-pong)
constexpr size_t OFF_PART = OFF_SC   + 2*64*1024*4;          // 2 x 64x8x130 f32 (m,S,ctx[128]) (ping-pong)

DI float bf2f(u16 u){ unsigned int v = ((unsigned int)u) << 16; return __uint_as_float(v); }
DI u16 f2bf(float f){ unsigned int u = __float_as_uint(f); unsigned int r = (u + 0x7FFFu + ((u>>16)&1u)) >> 16; return (u16)r; }
DI float sigm(float x){ return 1.f/(1.f + __expf(-x)); }
DI float tanh_(float x){ return 1.f - 2.f/(__expf(2.f*x) + 1.f); }

// frag slot for an A-operand element [row m][k]: lane=(m&15)|(((k>>3)&3)<<4), i=k&7, ktile=k>>5, mtile=m>>4
DI int fragIdx(int m, int k){ return (((k>>5)*4 + (m>>4))*64 + ((m&15) | (((k>>3)&3)<<4)))*8 + (k&7); }

// ---------------- one-time weight prep ----------------
__global__ __launch_bounds__(256) void kPrep(char* ws,
    const float* W1, const float* Wih, const float* Whh, const float* W2,
    const float* Wq, const float* bq, const float* Wk, const float* bk,
    const float* Wv, const float* bv, const float* W3, const float* b3,
    const float* bih, const float* bhh, const float* c0, const float* h0)
{
  const int wg = blockIdx.x, tid = threadIdx.x;
  if (wg < 64) {                       // Wkq[e][d] = scale * dot(Wk row e, Wq row d)
    float* Wkq = (float*)(ws + OFF_WKQ);
    for (int rr = 0; rr < 4; ++rr) {
      const int e = wg*4 + rr;
      float acc = 0.f;
      for (int d = 0; d < 256; ++d) acc = fmaf(Wk[e*256+d], Wq[tid*256+d], acc);
      Wkq[e*256 + tid] = acc * 0.0625f;
    }
  } else if (wg < 96) {                // Wvw[e][o] = dot(Wv row e, W3 col o)
    float* Wvw = (float*)(ws + OFF_WVW);
    if (tid < 128) {
      for (int rr = 0; rr < 8; ++rr) {
        const int e = (wg-64)*8 + rr;
        float acc = 0.f;
        for (int d = 0; d < 256; ++d) acc = fmaf(Wv[e*256+d], W3[d*128+tid], acc);
        Wvw[e*128 + tid] = acc;
      }
    }
  } else if (wg == 96) {               // wb, byv
    float* wb = (float*)(ws + OFF_WB);
    float acc = 0.f;
    for (int d = 0; d < 256; ++d) acc = fmaf(Wk[tid*256+d], bq[d], acc);
    wb[tid] = acc * 0.0625f;
    if (tid < 128) {
      float* byv = (float*)(ws + OFF_BYV);
      float a2 = b3[tid];
      for (int d = 0; d < 256; ++d) a2 = fmaf(bv[d], W3[d*128+tid], a2);
      byv[tid] = a2;
    }
  } else if (wg == 97) {               // bg = bih + bhh
    float* bg = (float*)(ws + OFF_BG);
    for (int j = tid; j < 2048; j += 256) bg[j] = bih[j] + bhh[j];
  } else if (wg < 106) {               // W2 -> W2T bf16, [n][k] layout
    u16* W2T = (u16*)(ws + OFF_W2T);
    const int n0 = (wg - 98)*32;
    for (int nn = 0; nn < 32; ++nn) {
      const int n = n0 + nn;
      for (int k = tid; k < 512; k += 256) W2T[n*512 + k] = f2bf(W2[k*256 + n]);
    }
  } else if (wg < 122) {               // W1 frag swizzle (B-operand)
    u16* W1f = (u16*)(ws + OFF_W1F);
    const int nt2 = wg - 106;
    for (int idx = tid; idx < 4*512; idx += 256) {
      const int kt2 = idx >> 9, rem = idx & 511, lane = rem >> 3, i = rem & 7;
      const int k = kt2*32 + (lane>>4)*8 + i, n = nt2*16 + (lane&15);
      W1f[((nt2*4+kt2)*64+lane)*8+i] = f2bf(W1[k*256+n]);
    }
  } else if (wg < 250) {               // Wih frag swizzle, gate-interleaved col permutation
    u16* Wihf = (u16*)(ws + OFF_WIHF);
    const int nt = wg - 122;
    for (int idx = tid; idx < 8*512; idx += 256) {
      const int kt = idx >> 9, rem = idx & 511, lane = rem >> 3, i = rem & 7;
      const int k = kt*32 + (lane>>4)*8 + i, r = lane & 15;
      const int gcol = (r>>2)*512 + nt*4 + (r&3);   // r: 0..3=i,4..7=f,8..11=g,12..15=o
      Wihf[((nt*8+kt)*64+lane)*8+i] = f2bf(Wih[k*2048 + gcol]);
    }
  } else if (wg < 378) {               // Whh frag swizzle
    u16* Whhf = (u16*)(ws + OFF_WHHF);
    const int nt = wg - 250;
    for (int idx = tid; idx < 16*512; idx += 256) {
      const int kt = idx >> 9, rem = idx & 511, lane = rem >> 3, i = rem & 7;
      const int k = kt*32 + (lane>>4)*8 + i, r = lane & 15;
      const int gcol = (r>>2)*512 + nt*4 + (r&3);
      Whhf[((nt*16+kt)*64+lane)*8+i] = f2bf(Whh[k*2048 + gcol]);
    }
  } else if (wg < 410) {               // state init: c0 -> cbuf, h0 -> hfrag[0]
    float* cb = (float*)(ws + OFF_CB);
    u16* hfr0 = (u16*)(ws + OFF_HFR);
    const int base = (wg - 378)*1024;
    for (int ii = tid; ii < 1024; ii += 256) {
      const int idx = base + ii, b = idx >> 9, j = idx & 511;
      cb[idx] = c0[idx];
      hfr0[fragIdx(b, j)] = f2bf(h0[idx]);
    }
  }
}

// ---------------- precompute kt, vw, s0 (mask bias folded in) ----------------
__global__ __launch_bounds__(256) void kKTVW(char* __restrict__ ws, const float* __restrict__ hid_r,
                                             const float* __restrict__ in_mask)
{
  const int wg = blockIdx.x, tid = threadIdx.x;
  __shared__ float lh[256*36];  // [e][r], padded to 36
  const float* Wkq = (const float*)(ws + OFF_WKQ);
  const float* Wvw = (const float*)(ws + OFF_WVW);
  const float* wb  = (const float*)(ws + OFF_WB);
  u16* kt = (u16*)(ws + OFF_KT);
  u16* vw = (u16*)(ws + OFF_VW);
  float* s0 = (float*)(ws + OFF_S0);
  const size_t r0 = (size_t)wg * 32;
  for (int idx = tid; idx < 32*256; idx += 256) {
    const int e = idx & 255, r = idx >> 8;
    lh[e*36 + r] = hid_r[(r0 + r)*256 + e];
  }
  __syncthreads();
  float acc[32];
  #pragma unroll
  for (int r = 0; r < 32; ++r) acc[r] = 0.f;
  for (int e = 0; e < 256; ++e) {
    const float wv = Wkq[e*256 + tid];
    #pragma unroll
    for (int r4 = 0; r4 < 8; ++r4) {
      const float4 l4 = *(const float4*)&lh[e*36 + r4*4];
      acc[r4*4+0] = fmaf(l4.x, wv, acc[r4*4+0]);
      acc[r4*4+1] = fmaf(l4.y, wv, acc[r4*4+1]);
      acc[r4*4+2] = fmaf(l4.z, wv, acc[r4*4+2]);
      acc[r4*4+3] = fmaf(l4.w, wv, acc[r4*4+3]);
    }
  }
  for (int r = 0; r < 32; ++r) kt[(r0 + r)*256 + tid] = f2bf(acc[r]);
  if (tid < 128) {
    #pragma unroll
    for (int r = 0; r < 32; ++r) acc[r] = 0.f;
    for (int e = 0; e < 256; ++e) {
      const float wv = Wvw[e*128 + tid];
      #pragma unroll
      for (int r4 = 0; r4 < 8; ++r4) {
        const float4 l4 = *(const float4*)&lh[e*36 + r4*4];
        acc[r4*4+0] = fmaf(l4.x, wv, acc[r4*4+0]);
        acc[r4*4+1] = fmaf(l4.y, wv, acc[r4*4+1]);
        acc[r4*4+2] = fmaf(l4.z, wv, acc[r4*4+2]);
        acc[r4*4+3] = fmaf(l4.w, wv, acc[r4*4+3]);
      }
    }
    for (int r = 0; r < 32; ++r) vw[(r0 + r)*128 + tid] = f2bf(acc[r]);
  } else if (tid < 160) {
    const int r = tid - 128;
    float a3 = 0.f;
    for (int e = 0; e < 256; ++e) a3 = fmaf(lh[e*36 + r], wb[e], a3);
    s0[r0 + r] = a3 + (in_mask[r0 + r] == 0.f ? -1e9f : 0.f);
  }
}

// ---------------- kA: gates WGs (0-63) + writer WGs (64-127)   (128 WGs x 1024 thr) ----------------
__global__ __launch_bounds__(1024) void kA(char* __restrict__ ws, const float* __restrict__ init_in,
                                           const float* __restrict__ in_mask, const float* __restrict__ b1,
                                           float* __restrict__ dout, int s)
{
  const int wg = blockIdx.x, tid = threadIdx.x;
  const float* part = (const float*)(ws + OFF_PART) + (size_t)((s+1)&1)*(64*8*130);
  const float* byv = (const float*)(ws + OFF_BYV);

  if (wg >= 64) {   // ---- writer WG: outputs for t = s-1 (runs on CUs the gates GEMM never uses) ----
    if (s == 0) return;
    const int b = wg - 64, t = s - 1;
    const float* scp = (const float*)(ws + OFF_SC) + (size_t)((s+1)&1)*(64*1024);
    float pm[8], pS[8], m = -1e30f;
    #pragma unroll
    for (int c = 0; c < 8; ++c) { pm[c] = part[(b*8+c)*130]; pS[c] = part[(b*8+c)*130+1]; m = fmaxf(m, pm[c]); }
    float Sv = 0.f;
    #pragma unroll
    for (int c = 0; c < 8; ++c) Sv += pS[c] * __expf(pm[c]-m);
    const float inv = 1.f / Sv;
    float* attn = dout + (size_t)64*1024*128;
    __builtin_nontemporal_store(__expf(scp[b*1024 + tid] - m) * inv,
                                &attn[((size_t)b*1024 + t)*1024 + tid]);
    if (tid < 128) {
      float a2 = 0.f;
      #pragma unroll
      for (int c = 0; c < 8; ++c) a2 += __expf(pm[c]-m) * part[(b*8+c)*130+2+tid];
      const float y = fmaxf(a2*inv + byv[tid], 0.f);
      __builtin_nontemporal_store(y * in_mask[b*1024 + t],
                                  &dout[((size_t)b*1024 + t)*128 + tid]);
    }
    return;
  }

  // ---- gates WG ----
  __shared__ union {
    u16 yfrag[16*64*8];                                       // stages 1-2 (16 KB)
    struct { float gmerge[8*64*4]; float gtile[64*32]; } s3;  // stages 3-4 (16 KB)
  } shmU;
  __shared__ union {
    u16 afrag[32*64*8];                                       // stages 2-3 (32 KB)
    float lfac[64*8];                                         // stage 1 only
  } shmV;

  // stage 1: y -> yfrag (bf16 A-operand layout)
  if (s == 0) {
    for (int idx = tid; idx < 64*128; idx += 1024) {
      const int b = idx >> 7, d0 = idx & 127;
      shmU.yfrag[fragIdx(b, d0)] = f2bf(init_in[b*128 + d0]);
    }
  } else {
    if (tid < 64) {
      const int b = tid;
      float pm[8], m = -1e30f;
      #pragma unroll
      for (int c = 0; c < 8; ++c) { pm[c] = part[(b*8+c)*130]; m = fmaxf(m, pm[c]); }
      float Sv = 0.f, pf[8];
      #pragma unroll
      for (int c = 0; c < 8; ++c) { pf[c] = __expf(pm[c]-m); Sv += part[(b*8+c)*130+1]*pf[c]; }
      const float inv = 1.f/Sv;
      #pragma unroll
      for (int c = 0; c < 8; ++c) shmV.lfac[b*8+c] = pf[c]*inv;
    }
    __syncthreads();
    for (int idx = tid; idx < 64*128; idx += 1024) {
      const int b = idx >> 7, d0 = idx & 127;
      float a2 = byv[d0];
      #pragma unroll
      for (int c = 0; c < 8; ++c) a2 += shmV.lfac[b*8+c]*part[(b*8+c)*130+2+d0];
      shmU.yfrag[fragIdx(b, d0)] = f2bf(fmaxf(a2, 0.f));
    }
  }
  __syncthreads();
  const int w = tid >> 6, lane = tid & 63;
  // stage 2: a = relu(y@W1 + b1); 16 waves cover 64 (mt,nt2) tiles
  {
    const u16* W1f = (const u16*)(ws + OFF_W1F);
    const int mt = w & 3, nb0 = w >> 2;
    for (int k = 0; k < 4; ++k) {
      const int nt2 = nb0 + k*4;
      f32x4 acc = {0.f,0.f,0.f,0.f};
      #pragma unroll
      for (int kt2 = 0; kt2 < 4; ++kt2) {
        bf16x8 av = *(const bf16x8*)&shmU.yfrag[((kt2*4+mt)*64+lane)*8];
        bf16x8 bv = *(const bf16x8*)&W1f[((nt2*4+kt2)*64+lane)*8];
        acc = __builtin_amdgcn_mfma_f32_16x16x32_bf16(av, bv, acc, 0, 0, 0);
      }
      const int col = nt2*16 + (lane&15);
      const float bb = b1[col];
      #pragma unroll
      for (int i = 0; i < 4; ++i) {
        const int b = mt*16 + (lane>>4)*4 + i;
        shmV.afrag[fragIdx(b, col)] = f2bf(fmaxf(acc[i] + bb, 0.f));
      }
    }
  }
  __syncthreads();
  // stage 3: gates 64x32 tile = a@Wih + h@Whh + bg; 16 waves: (mt, ntile, khalf)
  {
    const u16* Wihf = (const u16*)(ws + OFF_WIHF);
    const u16* Whhf = (const u16*)(ws + OFF_WHHF);
    const u16* hfr = (const u16*)(ws + OFF_HFR) + (size_t)(s & 1)*(16*4*64*8);
    const int mt = w & 3, ntile = (w>>2) & 1, khalf = w >> 3;
    const int nt = wg*2 + ntile;
    f32x4 acc = {0.f,0.f,0.f,0.f};
    if (khalf == 0) {
      for (int kt = 0; kt < 8; ++kt) {
        bf16x8 av = *(const bf16x8*)&shmV.afrag[((kt*4+mt)*64+lane)*8];
        bf16x8 bv = *(const bf16x8*)&Wihf[((nt*8+kt)*64+lane)*8];
        acc = __builtin_amdgcn_mfma_f32_16x16x32_bf16(av, bv, acc, 0, 0, 0);
      }
      for (int kt = 0; kt < 4; ++kt) {
        bf16x8 av = *(const bf16x8*)&hfr[((kt*4+mt)*64+lane)*8];
        bf16x8 bv = *(const bf16x8*)&Whhf[((nt*16+kt)*64+lane)*8];
        acc = __builtin_amdgcn_mfma_f32_16x16x32_bf16(av, bv, acc, 0, 0, 0);
      }
    } else {
      for (int kt = 4; kt < 16; ++kt) {
        bf16x8 av = *(const bf16x8*)&hfr[((kt*4+mt)*64+lane)*8];
        bf16x8 bv = *(const bf16x8*)&Whhf[((nt*16+kt)*64+lane)*8];
        acc = __builtin_amdgcn_mfma_f32_16x16x32_bf16(av, bv, acc, 0, 0, 0);
      }
      #pragma unroll
      for (int i = 0; i < 4; ++i) shmU.s3.gmerge[((ntile*4+mt)*64+lane)*4+i] = acc[i];
    }
    __syncthreads();
    if (khalf == 0) {
      const float* bg = (const float*)(ws + OFF_BG);
      const int r = lane & 15;
      const float bb = bg[(r>>2)*512 + nt*4 + (r&3)];
      #pragma unroll
      for (int i = 0; i < 4; ++i) {
        const int b = mt*16 + (lane>>4)*4 + i;
        shmU.s3.gtile[b*32 + ntile*16 + r] = acc[i] + shmU.s3.gmerge[((ntile*4+mt)*64+lane)*4+i] + bb;
      }
    }
  }
  __syncthreads();
  // stage 4: h,c pointwise; 256 threads x 2 cols -> packed stores
  if (tid < 256) {
    const int b = tid >> 2, jj2 = tid & 3;
    float* cb = (float*)(ws + OFF_CB);
    float* hf = (float*)(ws + OFF_HF);
    u16* hfw = (u16*)(ws + OFF_HFR) + (size_t)((s & 1) ^ 1)*(16*4*64*8);
    float hv[2];
    #pragma unroll
    for (int t2 = 0; t2 < 2; ++t2) {
      const int jj = jj2*2 + t2;
      const int j = wg*8 + jj;
      const int cb32 = b*32 + (jj>>2)*16 + (jj&3);
      const float ig = shmU.s3.gtile[cb32 + 0];
      const float fg = shmU.s3.gtile[cb32 + 4];
      const float gg = shmU.s3.gtile[cb32 + 8];
      const float og = shmU.s3.gtile[cb32 + 12];
      const float cold = cb[b*512 + j];
      const float cnew = sigm(fg)*cold + sigm(ig)*tanh_(gg);
      hv[t2] = sigm(og)*tanh_(cnew);
      cb[b*512 + j] = cnew;
    }
    const int j0 = wg*8 + jj2*2;
    *(float2*)&hf[b*512 + j0] = make_float2(hv[0], hv[1]);
    const u32 pw = (u32)f2bf(hv[0]) | ((u32)f2bf(hv[1]) << 16);
    *(u32*)&hfw[fragIdx(b, j0)] = pw;
  }
}

// ---------------- kB: dx + flash attention, 128-key chunks (512 WGs x 512 thr, 2 WGs/CU) ----------------
__global__ __launch_bounds__(512, 4) void kB(char* __restrict__ ws, const float* __restrict__ b2, int s)
{
  const int wg = blockIdx.x, tid = threadIdx.x;
  const int b = wg >> 3, ch = wg & 7;          // batch, 128-key chunk
  const int hl = tid & 31, unit = tid >> 5;    // lane, unit 0..15
  __shared__ union { float red[256*33]; float mrg[16*132]; } U;
  __shared__ float dxl[256];

  const u16* kt = (const u16*)(ws + OFF_KT);
  const u16* vw = (const u16*)(ws + OFF_VW);
  const float* s0 = (const float*)(ws + OFF_S0);
  float* partc = (float*)(ws + OFF_PART) + (size_t)(s&1)*(64*8*130);
  float* scc   = (float*)(ws + OFF_SC)   + (size_t)(s&1)*(64*1024);

  // ---- issue full KV stream first: sched_barrier pins these loads ABOVE dx so HBM/L3 latency
  //      hides under dx compute (R10's version: compiler sank them to their uses — VGPR=64 proof) ----
  u16x8 kvr[8]; u16x4 vvr[8]; float s0r[8];
  #pragma unroll
  for (int i = 0; i < 8; ++i) {
    const int l = ch*128 + i*16 + unit;        // unit-major: adjacent units read adjacent rows
    const size_t row = (size_t)b*1024 + l;
    kvr[i] = *(const u16x8*)(kt + row*256 + hl*8);
    vvr[i] = *(const u16x4*)(vw + row*128 + hl*4);
    s0r[i] = s0[row];
  }
  __builtin_amdgcn_sched_barrier(0);   // nothing crosses: KV loads stay issued before dx

  // ---- dx = relu(h[b]@W2 + b2): unit u computes cols u*16..u*16+15, lane hl owns k=hl*16..+15 ----
  {
    const float* hb = (const float*)(ws + OFF_HF) + b*512;
    const u16* W2T = (const u16*)(ws + OFF_W2T);
    float hreg[16];
    #pragma unroll
    for (int i = 0; i < 4; ++i) {
      const float4 h4 = *(const float4*)(hb + hl*16 + i*4);
      hreg[i*4+0] = h4.x; hreg[i*4+1] = h4.y; hreg[i*4+2] = h4.z; hreg[i*4+3] = h4.w;
    }
    #pragma unroll
    for (int j = 0; j < 16; ++j) {
      const int n = unit*16 + j;
      const u16x8 w0 = *(const u16x8*)(W2T + n*512 + hl*16);
      const u16x8 w1 = *(const u16x8*)(W2T + n*512 + hl*16 + 8);
      float acc = 0.f;
      #pragma unroll
      for (int i2 = 0; i2 < 8; ++i2) acc = fmaf(hreg[i2], bf2f(w0[i2]), acc);
      #pragma unroll
      for (int i2 = 0; i2 < 8; ++i2) acc = fmaf(hreg[8+i2], bf2f(w1[i2]), acc);
      U.red[n*33 + hl] = acc;   // pad-33: bank-conflict-free
    }
  }
  __syncthreads();
  if (tid < 256) {
    float acc = 0.f;
    #pragma unroll
    for (int l = 0; l < 32; ++l) acc += U.red[tid*33 + l];
    dxl[tid] = fmaxf(acc + b2[tid], 0.f);
  }
  __syncthreads();

  // ---- flash attention over this WG's 128-key chunk: batch-8 softmax per unit ----
  float dxv[8];
  {
    const float4 d0 = *(const float4*)&dxl[hl*8];
    const float4 d1 = *(const float4*)&dxl[hl*8+4];
    dxv[0]=d0.x; dxv[1]=d0.y; dxv[2]=d0.z; dxv[3]=d0.w;
    dxv[4]=d1.x; dxv[5]=d1.y; dxv[6]=d1.z; dxv[7]=d1.w;
  }
  float sums[8];
  #pragma unroll
  for (int i = 0; i < 8; ++i) {
    float sum = 0.f;
    #pragma unroll
    for (int j2 = 0; j2 < 8; ++j2) sum = fmaf(bf2f(kvr[i][j2]), dxv[j2], sum);
    #pragma unroll
    for (int d = 1; d < 32; d <<= 1) sum += __shfl_xor(sum, d, 64);
    sums[i] = sum + s0r[i];
  }
  float keep = 0.f;
  #pragma unroll
  for (int i = 0; i < 8; ++i) if (hl == i) keep = sums[i];
  float m = sums[0];
  #pragma unroll
  for (int i = 1; i < 8; ++i) m = fmaxf(m, sums[i]);
  float S = 0.f, cx0 = 0.f, cx1 = 0.f, cx2 = 0.f, cx3 = 0.f;
  #pragma unroll
  for (int i = 0; i < 8; ++i) {
    const float e2 = __expf(sums[i] - m);
    S += e2;
    cx0 = fmaf(e2, bf2f(vvr[i][0]), cx0);
    cx1 = fmaf(e2, bf2f(vvr[i][1]), cx1);
    cx2 = fmaf(e2, bf2f(vvr[i][2]), cx2);
    cx3 = fmaf(e2, bf2f(vvr[i][3]), cx3);
  }
  if (hl < 8) scc[b*1024 + ch*128 + hl*16 + unit] = keep;
  U.mrg[unit*132 + 4 + hl*4 + 0] = cx0;
  U.mrg[unit*132 + 4 + hl*4 + 1] = cx1;
  U.mrg[unit*132 + 4 + hl*4 + 2] = cx2;
  U.mrg[unit*132 + 4 + hl*4 + 3] = cx3;
  if (hl == 0) { U.mrg[unit*132] = m; U.mrg[unit*132+1] = S; }
  __syncthreads();
  if (tid < 128) {   // merge 16 unit-partials -> chunk partial
    float mg = -1e30f;
    for (int u = 0; u < 16; ++u) mg = fmaxf(mg, U.mrg[u*132]);
    float Sg = 0.f, cx = 0.f;
    for (int u = 0; u < 16; ++u) {
      const float f = __expf(U.mrg[u*132] - mg);
      Sg = fmaf(U.mrg[u*132+1], f, Sg);
      cx = fmaf(f, U.mrg[u*132 + 4 + tid], cx);
    }
    partc[(b*8+ch)*130 + 2 + tid] = cx;
    if (tid == 0) { partc[(b*8+ch)*130] = mg; partc[(b*8+ch)*130+1] = Sg; }
  }
}

// ---------------- kWLast: writer for t=1023 (64 WGs x 1024 thr) ----------------
__global__ __launch_bounds__(1024) void kWLast(char* __restrict__ ws, const float* __restrict__ in_mask,
                                               float* __restrict__ dout)
{
  const int b = blockIdx.x, tid = threadIdx.x;
  const float* part = (const float*)(ws + OFF_PART) + (size_t)(1023&1)*(64*8*130);
  const float* sc   = (const float*)(ws + OFF_SC)   + (size_t)(1023&1)*(64*1024);
  float pm[8], pS[8], m = -1e30f;
  #pragma unroll
  for (int c = 0; c < 8; ++c) { pm[c] = part[(b*8+c)*130]; pS[c] = part[(b*8+c)*130+1]; m = fmaxf(m, pm[c]); }
  float Sv = 0.f;
  #pragma unroll
  for (int c = 0; c < 8; ++c) Sv += pS[c] * __expf(pm[c]-m);
  const float inv = 1.f / Sv;
  float* attn = dout + (size_t)64*1024*128;
  __builtin_nontemporal_store(__expf(sc[b*1024 + tid] - m) * inv,
                              &attn[((size_t)b*1024 + 1023)*1024 + tid]);
  if (tid < 128) {
    const float* byv = (const float*)(ws + OFF_BYV);
    float a2 = 0.f;
    #pragma unroll
    for (int c = 0; c < 8; ++c) a2 += __expf(pm[c]-m) * part[(b*8+c)*130+2+tid];
    const float y = fmaxf(a2*inv + byv[tid], 0.f);
    __builtin_nontemporal_store(y * in_mask[b*1024 + 1023],
                                &dout[((size_t)b*1024 + 1023)*128 + tid]);
  }
}

extern "C" void kernel_launch(void* const* d_in, const int* in_sizes, int n_in,
                              void* d_out, int out_size, void* d_ws, size_t ws_size,
                              hipStream_t stream)
{
  (void)in_sizes; (void)n_in; (void)out_size; (void)ws_size;
  const float* hid_r  = (const float*)d_in[0];
  const float* in_mask= (const float*)d_in[1];
  const float* init_in= (const float*)d_in[2];
  const float* h0     = (const float*)d_in[3];
  const float* c0     = (const float*)d_in[4];
  const float* W1     = (const float*)d_in[5];
  const float* b1     = (const float*)d_in[6];
  const float* Wih    = (const float*)d_in[7];
  const float* Whh    = (const float*)d_in[8];
  const float* bih    = (const float*)d_in[9];
  const float* bhh    = (const float*)d_in[10];
  const float* W2     = (const float*)d_in[11];
  const float* b2     = (const float*)d_in[12];
  const float* Wq     = (const float*)d_in[13];
  const float* bq     = (const float*)d_in[14];
  const float* Wk     = (const float*)d_in[15];
  const float* bk     = (const float*)d_in[16];
  const float* Wv     = (const float*)d_in[17];
  const float* bv     = (const float*)d_in[18];
  const float* W3     = (const float*)d_in[19];
  const float* b3     = (const float*)d_in[20];
  char* ws = (char*)d_ws;
  float* out = (float*)d_out;

  hipLaunchKernelGGL(kPrep, dim3(410), dim3(256), 0, stream, ws,
                     W1, Wih, Whh, W2, Wq, bq, Wk, bk, Wv, bv, W3, b3, bih, bhh, c0, h0);
  hipLaunchKernelGGL(kKTVW, dim3(2048), dim3(256), 0, stream, ws, hid_r, in_mask);
  for (int s = 0; s < 1024; ++s) {
    hipLaunchKernelGGL(kA, dim3(128), dim3(1024), 0, stream, ws, init_in, in_mask, b1, out, s);
    hipLaunchKernelGGL(kB, dim3(512), dim3(512), 0, stream, ws, b2, s);
  }
  hipLaunchKernelGGL(kWLast, dim3(64), dim3(1024), 0, stream, ws, in_mask, out);
}